// Round 4
// baseline (172.647 us; speedup 1.0000x reference)
//
#include <hip/hip_runtime.h>
#include <math.h>

#define BB   1024
#define MM   32
#define HH   2
#define DD   64
#define NREL 32
#define TBB  32          // b-tile per block in kernel A

// ---------------- Kernel A: Q[b][r][j] = sum_i item[b][i] * R[r][i][j] -----
// grid = (BB/TBB, NREL), block = 256.  ~2-3 us, near the 268 MFLOP vector
// compute floor (157 TF -> 1.7 us).
__global__ __launch_bounds__(256) void compute_q(
    const int* __restrict__ edge_index,     // (B,2)
    const float* __restrict__ entity_emb,   // (N_ENT, D)
    const float* __restrict__ relation_emb, // (NREL, D*D)
    float* __restrict__ qout)               // (B, NREL, D)
{
    __shared__ float R_s[DD * DD];          // 16 KB, row-major R[i][j]
    __shared__ float item_s[TBB * 68];      // stride 68: 16B-aligned, banks spread

    const int r   = blockIdx.y;
    const int b0  = blockIdx.x * TBB;
    const int tid = threadIdx.x;

    // stage R_r: 1024 float4, 4 per thread (coalesced; 512 KB table L2-hot)
    const float4* Rg = (const float4*)(relation_emb + (size_t)r * DD * DD);
    #pragma unroll
    for (int k = 0; k < 4; ++k)
        ((float4*)R_s)[tid + 256 * k] = Rg[tid + 256 * k];

    // stage 32 item rows: 512 float4, 2 per thread
    #pragma unroll
    for (int k = 0; k < 2; ++k) {
        int idx = tid + 256 * k;            // 0..511
        int bl  = idx >> 4;                 // 0..31
        int c4  = idx & 15;                 // 0..15
        int ei  = edge_index[2 * (b0 + bl) + 1];
        ((float4*)(item_s + bl * 68))[c4] =
            *(const float4*)(entity_emb + (size_t)ei * DD + c4 * 4);
    }
    __syncthreads();

    // each thread: j-chunk j4..j4+3 for b-locals bl0 and bl0+16
    const int j4  = (tid & 15) * 4;
    const int bl0 = tid >> 4;               // 0..15
    float4 acc0 = {0.f, 0.f, 0.f, 0.f};
    float4 acc1 = {0.f, 0.f, 0.f, 0.f};
    #pragma unroll 8
    for (int i = 0; i < DD; ++i) {
        const float4 rv = *(const float4*)(R_s + i * DD + j4);
        const float a0 = item_s[bl0 * 68 + i];
        const float a1 = item_s[(bl0 + 16) * 68 + i];
        acc0.x += a0 * rv.x; acc0.y += a0 * rv.y;
        acc0.z += a0 * rv.z; acc0.w += a0 * rv.w;
        acc1.x += a1 * rv.x; acc1.y += a1 * rv.y;
        acc1.z += a1 * rv.z; acc1.w += a1 * rv.w;
    }
    size_t q0 = ((size_t)(b0 + bl0) * NREL + r) * DD + j4;
    size_t q1 = ((size_t)(b0 + bl0 + 16) * NREL + r) * DD + j4;
    *(float4*)(qout + q0) = acc0;
    *(float4*)(qout + q1) = acc1;
}

// ---------------- Kernel B: gather + in-register dots + softmax ------------
// out[b] = sum_t softmax_m(v)[t] * dot(h_t, item);  v_t = dot(h_t, q_rel_t).
// u is never materialized: both dots are formed during the gather (4-elem
// partials + 16-lane xor-shuffle reduce). No big LDS, 2 phases, 1 barrier.
__global__ __launch_bounds__(256) void ripple_apply(
    const int* __restrict__ edge_index,
    const int* __restrict__ ripple_sets,    // (H,B,M,2) int32
    const float* __restrict__ entity_emb,
    const float* __restrict__ qg,           // (B, NREL, D)
    float* __restrict__ out)                // (B,1)
{
    __shared__ float v_s[HH * MM];
    __shared__ float w_s[HH * MM];

    const int b   = blockIdx.x;
    const int tid = threadIdx.x;
    const int c4  = tid & 15;

    // item chunk for this thread's column group (broadcast within 16-thread
    // groups; row is L1/L2-hot after first wave touches it)
    const int item_idx = edge_index[2 * b + 1];
    const float4 iv = *(const float4*)(entity_emb + (size_t)item_idx * DD + c4 * 4);

    #pragma unroll
    for (int k = 0; k < 4; ++k) {
        int idx = tid + 256 * k;            // 0..1023
        int row = idx >> 4;                 // t: 0..63
        int hop = row >> 5, m = row & 31;
        size_t ibase = (size_t)(hop * BB + b) * MM + m;
        const int2 hr = ((const int2*)ripple_sets)[ibase];   // {head, rel}
        const float4 hv = *(const float4*)(entity_emb + (size_t)hr.x * DD + c4 * 4);
        const float4 qv = *(const float4*)(qg + ((size_t)b * NREL + hr.y) * DD + c4 * 4);
        float sv = hv.x * qv.x + hv.y * qv.y + hv.z * qv.z + hv.w * qv.w;
        float sw = hv.x * iv.x + hv.y * iv.y + hv.z * iv.z + hv.w * iv.w;
        // reduce over the 16 lanes sharing this row (xor<=8 stays in group)
        #pragma unroll
        for (int off = 8; off > 0; off >>= 1) {
            sv += __shfl_xor(sv, off, 64);
            sw += __shfl_xor(sw, off, 64);
        }
        if (c4 == 0) { v_s[row] = sv; w_s[row] = sw; }
    }
    __syncthreads();

    // wave 0: lane t holds (v,w) for pair t. Softmax over each 32-lane hop
    // half (xor<=16 stays in half), then sum p*w over all 64 lanes.
    if (tid < HH * MM) {
        float v = v_s[tid];
        float w = w_s[tid];
        float mx = v;
        #pragma unroll
        for (int off = 16; off > 0; off >>= 1)
            mx = fmaxf(mx, __shfl_xor(mx, off, 64));
        float e = expf(v - mx);
        float s = e;
        #pragma unroll
        for (int off = 16; off > 0; off >>= 1)
            s += __shfl_xor(s, off, 64);
        float contrib = (e / s) * w;
        #pragma unroll
        for (int off = 32; off > 0; off >>= 1)
            contrib += __shfl_xor(contrib, off, 64);
        if (tid == 0) out[b] = contrib;
    }
}

extern "C" void kernel_launch(void* const* d_in, const int* in_sizes, int n_in,
                              void* d_out, int out_size, void* d_ws, size_t ws_size,
                              hipStream_t stream) {
    const int*   edge_index   = (const int*)d_in[0];
    const int*   ripple_sets  = (const int*)d_in[1];
    const float* entity_emb   = (const float*)d_in[2];
    const float* relation_emb = (const float*)d_in[3];
    float* out = (float*)d_out;
    float* qbuf = (float*)d_ws;             // B*NREL*D floats = 8 MB
    (void)in_sizes; (void)n_in; (void)out_size; (void)ws_size;

    compute_q<<<dim3(BB / TBB, NREL), dim3(256), 0, stream>>>(
        edge_index, entity_emb, relation_emb, qbuf);
    ripple_apply<<<dim3(BB), dim3(256), 0, stream>>>(
        edge_index, ripple_sets, entity_emb, qbuf, out);
}

// Round 5
// 171.020 us; speedup vs baseline: 1.0095x; 1.0095x over previous
//
#include <hip/hip_runtime.h>
#include <math.h>

#define BB   1024
#define MM   32
#define HH   2
#define DD   64
#define NREL 32
#define TBB  32          // b-tile per block in kernel A

// ---------------- Kernel A: Q[b][r][j] = sum_i item[b][i] * R[r][i][j] -----
// grid = (BB/TBB, NREL), block = 256.  ~2-3 us, near the 268 MFLOP vector
// compute floor. Relation table read: 1024 blocks x 16 KB = 16 MB (L2-hot)
// vs 512 MB for the per-b variant — this split is the structural win.
__global__ __launch_bounds__(256) void compute_q(
    const int* __restrict__ edge_index,     // (B,2)
    const float* __restrict__ entity_emb,   // (N_ENT, D)
    const float* __restrict__ relation_emb, // (NREL, D*D)
    float* __restrict__ qout)               // (B, NREL, D)
{
    __shared__ float R_s[DD * DD];          // 16 KB, row-major R[i][j]
    __shared__ float item_s[TBB * 68];      // stride 68: 16B-aligned, banks spread

    const int r   = blockIdx.y;
    const int b0  = blockIdx.x * TBB;
    const int tid = threadIdx.x;

    // stage R_r: 1024 float4, 4 per thread (coalesced)
    const float4* Rg = (const float4*)(relation_emb + (size_t)r * DD * DD);
    #pragma unroll
    for (int k = 0; k < 4; ++k)
        ((float4*)R_s)[tid + 256 * k] = Rg[tid + 256 * k];

    // stage 32 item rows: 512 float4, 2 per thread
    #pragma unroll
    for (int k = 0; k < 2; ++k) {
        int idx = tid + 256 * k;            // 0..511
        int bl  = idx >> 4;                 // 0..31
        int c4  = idx & 15;                 // 0..15
        int ei  = edge_index[2 * (b0 + bl) + 1];
        ((float4*)(item_s + bl * 68))[c4] =
            *(const float4*)(entity_emb + (size_t)ei * DD + c4 * 4);
    }
    __syncthreads();

    // each thread: j-chunk j4..j4+3 for b-locals bl0 and bl0+16
    const int j4  = (tid & 15) * 4;
    const int bl0 = tid >> 4;               // 0..15
    float4 acc0 = {0.f, 0.f, 0.f, 0.f};
    float4 acc1 = {0.f, 0.f, 0.f, 0.f};
    #pragma unroll 8
    for (int i = 0; i < DD; ++i) {
        const float4 rv = *(const float4*)(R_s + i * DD + j4);
        const float a0 = item_s[bl0 * 68 + i];
        const float a1 = item_s[(bl0 + 16) * 68 + i];
        acc0.x += a0 * rv.x; acc0.y += a0 * rv.y;
        acc0.z += a0 * rv.z; acc0.w += a0 * rv.w;
        acc1.x += a1 * rv.x; acc1.y += a1 * rv.y;
        acc1.z += a1 * rv.z; acc1.w += a1 * rv.w;
    }
    size_t q0 = ((size_t)(b0 + bl0) * NREL + r) * DD + j4;
    size_t q1 = ((size_t)(b0 + bl0 + 16) * NREL + r) * DD + j4;
    *(float4*)(qout + q0) = acc0;
    *(float4*)(qout + q1) = acc1;
}

// ---------------- Kernel B: gather h + Q rows, softmax, combine ------------
// grid = BB, block = 256. Best-measured variant (R3, 170.65 us): LDS-staged
// rows, all phases parallel across 256 threads / 64 lanes.
#define HS 65   // odd stride: <=2-way bank aliasing everywhere (free on gfx950)

__global__ __launch_bounds__(256) void ripple_apply(
    const int* __restrict__ edge_index,
    const int* __restrict__ ripple_sets,    // (H,B,M,2) int32
    const float* __restrict__ entity_emb,
    const float* __restrict__ qg,           // (B, NREL, D)
    float* __restrict__ out)                // (B,1)
{
    __shared__ float item_s[DD];
    __shared__ float h_s[HH * MM * HS];     // 64 x 65
    __shared__ float q_s[HH * MM * HS];     // 64 x 65
    __shared__ float vp_s[4 * 64];          // v partials (quarter-dots)
    __shared__ float p_s[HH * MM];
    __shared__ float up_s[4 * 68];          // u partials

    const int b   = blockIdx.x;
    const int tid = threadIdx.x;

    if (tid < DD) {
        int item_idx = edge_index[2 * b + 1];       // broadcast, L2-hot
        item_s[tid] = entity_emb[(size_t)item_idx * DD + tid];
    }

    // gather h rows and Q rows: 64 rows x 16 float4 each; indices read
    // directly (16 threads share one row -> broadcast load, 512 KB L2-hot)
    #pragma unroll
    for (int k = 0; k < 4; ++k) {
        int idx = tid + 256 * k;            // 0..1023
        int row = idx >> 4;                 // t: 0..63
        int c4  = idx & 15;
        int hop = row >> 5, m = row & 31;
        size_t ibase = ((size_t)(hop * BB + b) * MM + m) * 2;
        int head = ripple_sets[ibase];
        int rel  = ripple_sets[ibase + 1];
        const float4 hv = *(const float4*)(entity_emb + (size_t)head * DD + c4 * 4);
        float* hd = h_s + row * HS + c4 * 4;
        hd[0] = hv.x; hd[1] = hv.y; hd[2] = hv.z; hd[3] = hv.w;
        const float4 qv = *(const float4*)(qg + ((size_t)b * NREL + rel) * DD + c4 * 4);
        float* qd = q_s + row * HS + c4 * 4;
        qd[0] = qv.x; qd[1] = qv.y; qd[2] = qv.z; qd[3] = qv.w;
    }
    __syncthreads();

    // v[t] = dot(Q_row[t], h[t]) -- split 4 ways: wave w does j-chunk w*16
    {
        int t = tid & 63;
        int q = tid >> 6;                   // 0..3
        const float* qp = q_s + t * HS + q * 16;
        const float* hp = h_s + t * HS + q * 16;
        float acc = 0.f;
        #pragma unroll
        for (int j = 0; j < 16; ++j) acc += qp[j] * hp[j];
        vp_s[q * 64 + t] = acc;
    }
    __syncthreads();

    // lane-parallel softmax: lane t holds v[t]; xor-offsets <=16 stay inside
    // each 32-lane half (= one hop)
    if (tid < HH * MM) {
        float v = vp_s[tid] + vp_s[64 + tid] + vp_s[128 + tid] + vp_s[192 + tid];
        float mx = v;
        #pragma unroll
        for (int off = 16; off > 0; off >>= 1)
            mx = fmaxf(mx, __shfl_xor(mx, off, 64));
        float e = expf(v - mx);
        float s = e;
        #pragma unroll
        for (int off = 16; off > 0; off >>= 1)
            s += __shfl_xor(s, off, 64);
        p_s[tid] = e / s;
    }
    __syncthreads();

    // u_d = sum_t p[t]*h[t][d] -- split 4 ways over t (16 t's per wave)
    {
        int d    = tid & 63;
        int part = tid >> 6;                // 0..3
        float u = 0.f;
        #pragma unroll
        for (int tt = 0; tt < 16; ++tt) {
            int t = part * 16 + tt;
            u += p_s[t] * h_s[t * HS + d];  // p_s broadcast; h_s 2-way
        }
        up_s[part * 68 + d] = u;
    }
    __syncthreads();

    if (tid < DD) {
        float u = up_s[tid] + up_s[68 + tid] + up_s[136 + tid] + up_s[204 + tid];
        float prod = u * item_s[tid];
        #pragma unroll
        for (int off = 32; off > 0; off >>= 1) prod += __shfl_down(prod, off, 64);
        if (tid == 0) out[b] = prod;
    }
}

extern "C" void kernel_launch(void* const* d_in, const int* in_sizes, int n_in,
                              void* d_out, int out_size, void* d_ws, size_t ws_size,
                              hipStream_t stream) {
    const int*   edge_index   = (const int*)d_in[0];
    const int*   ripple_sets  = (const int*)d_in[1];
    const float* entity_emb   = (const float*)d_in[2];
    const float* relation_emb = (const float*)d_in[3];
    float* out = (float*)d_out;
    float* qbuf = (float*)d_ws;             // B*NREL*D floats = 8 MB
    (void)in_sizes; (void)n_in; (void)out_size; (void)ws_size;

    compute_q<<<dim3(BB / TBB, NREL), dim3(256), 0, stream>>>(
        edge_index, entity_emb, relation_emb, qbuf);
    ripple_apply<<<dim3(BB), dim3(256), 0, stream>>>(
        edge_index, ripple_sets, entity_emb, qbuf, out);
}